// Round 4
// baseline (398.288 us; speedup 1.0000x reference)
//
#include <hip/hip_runtime.h>

#define DIM 1024
#define SEQ 4096
#define MROWS 16384      // BATCH * SEQ
#define CHUNK 64
#define NCHUNKBLKS 256   // MROWS / CHUNK

typedef float  f32x4  __attribute__((ext_vector_type(4)));
typedef __bf16 bf16x8 __attribute__((ext_vector_type(8)));
typedef __bf16 bf16x4 __attribute__((ext_vector_type(4)));

// async global->LDS, 16B per lane. LDS dest is wave-uniform base + lane*16.
__device__ __forceinline__ void gld16(const void* g, void* l) {
  __builtin_amdgcn_global_load_lds((__attribute__((address_space(1))) void*)g,
                                   (__attribute__((address_space(3))) void*)l,
                                   16, 0, 0);
}

__device__ __forceinline__ f32x4 ld4f(const __bf16* p) {
  bf16x4 v = *(const bf16x4*)p;
  f32x4 r;
#pragma unroll
  for (int j = 0; j < 4; ++j) r[j] = (float)v[j];
  return r;
}

// C[M,N] = A[M,DIM] (bf16) * Bt[N,DIM]^T (bf16), fp32 accumulate.
// MODE 0: out bf16 = acc + bias
// MODE 3: out f32  = acc + bias + xres[row][col]        (final residual)
// MODE 5: out bf16 = acc * ms                           (weight combine)
// MODE 7: out bf16 = wrap(base[row%SEQ][col] + acc + bias)  (phase, wrapped)
// Tile 128x128, 4 waves. T2: both-sides LDS XOR swizzle (chunk ^= (row>>1)&3).
// T3-minimum 2-phase: double-buffered LDS; issue next tile's global_load_lds
// BEFORE current tile's ds_read+MFMA; single vmcnt(0)-drain barrier per step.
// T1 (SWZ): XCD row-band remap for grid (8,128).
template <int MODE, bool SWZ>
__global__ __launch_bounds__(256, 2)
void gemm_bt(const __bf16* __restrict__ A, const __bf16* __restrict__ Bt,
             const float* __restrict__ bias, void* __restrict__ outp,
             const float* __restrict__ basep, const float* __restrict__ mscp,
             const float* __restrict__ xres)
{
  __shared__ __bf16 As[2 * 128 * 32];   // [buf][row][k], 16 KB
  __shared__ __bf16 Bs[2 * 128 * 32];
  const int tid  = threadIdx.x;
  const int lane = tid & 63;
  const int widx = tid >> 6;
  const int wr   = widx >> 1, wc = widx & 1;

  int row_t, col_t;
  if (SWZ) {
    const int b = blockIdx.y * 8 + blockIdx.x;   // grid must be (8,128)
    const int xcd = b & 7, slot = b >> 3;
    col_t = slot & 7;
    row_t = (xcd << 4) | (slot >> 3);
  } else {
    row_t = blockIdx.y; col_t = blockIdx.x;
  }
  const int row0 = row_t * 128, col0 = col_t * 128;

  // staging: lane l covers LDS bytes (buf*8192 + widx*1024 + i*4096 + l*16)
  //  -> row = widx*16 + i*64 + (l>>2); source chunk = (l&3) ^ ((l>>3)&3)
  const int kc = ((lane & 3) ^ ((lane >> 3) & 3)) * 8;
  const __bf16* Ag = A  + (size_t)(row0 + widx * 16 + (lane >> 2)) * DIM + kc;
  const __bf16* Bg = Bt + (size_t)(col0 + widx * 16 + (lane >> 2)) * DIM + kc;
  char* AsL = (char*)As + widx * 1024;
  char* BsL = (char*)Bs + widx * 1024;

  f32x4 acc[4][4] = {};
  const int ar = wr * 64 + (lane & 15);
  const int br = wc * 64 + (lane & 15);
  const int kg = lane >> 4;
  const int aidx = kg ^ ((ar >> 1) & 3);   // swizzled chunk (invariant under row+16)
  const int bidx = kg ^ ((br >> 1) & 3);

  // prologue: stage tile 0 into buffer 0
  gld16(Ag,            AsL);
  gld16(Ag + 64 * DIM, AsL + 4096);
  gld16(Bg,            BsL);
  gld16(Bg + 64 * DIM, BsL + 4096);
  __syncthreads();

  const int NT = DIM / 32;
  int cur = 0;
  for (int kt = 0; kt < NT; ++kt) {
    // phase 1: issue next tile's loads into the other buffer (overlaps compute)
    if (kt + 1 < NT) {
      const __bf16* a = Ag + (kt + 1) * 32;
      const __bf16* b = Bg + (kt + 1) * 32;
      char* An = AsL + (cur ^ 1) * 8192;
      char* Bn = BsL + (cur ^ 1) * 8192;
      gld16(a,            An);
      gld16(a + 64 * DIM, An + 4096);
      gld16(b,            Bn);
      gld16(b + 64 * DIM, Bn + 4096);
    }
    // phase 2: compute on current buffer
    const bf16x8* Avc = (const bf16x8*)(As + cur * 128 * 32);
    const bf16x8* Bvc = (const bf16x8*)(Bs + cur * 128 * 32);
    bf16x8 af[4], bfv[4];
#pragma unroll
    for (int i = 0; i < 4; ++i) af[i]  = Avc[(ar + i * 16) * 4 + aidx];
#pragma unroll
    for (int i = 0; i < 4; ++i) bfv[i] = Bvc[(br + i * 16) * 4 + bidx];
#pragma unroll
    for (int mi = 0; mi < 4; ++mi)
#pragma unroll
      for (int ni = 0; ni < 4; ++ni)
        acc[mi][ni] = __builtin_amdgcn_mfma_f32_16x16x32_bf16(af[mi], bfv[ni], acc[mi][ni], 0, 0, 0);
    // single drain per K-step: by now the staged loads have been hidden
    __syncthreads();
    cur ^= 1;
  }

  // C/D frag mapping (HW-verified): col = lane&15, row = (lane>>4)*4 + r
  const int ccol = col0 + wc * 64 + (lane & 15);
  const int crow = row0 + wr * 64 + kg * 4;
  float bvv[4];
  if (MODE != 5) {
#pragma unroll
    for (int ni = 0; ni < 4; ++ni) bvv[ni] = bias[ccol + ni * 16];
  }
  float ms = 0.f;
  if (MODE == 5) ms = mscp[0];
#pragma unroll
  for (int mi = 0; mi < 4; ++mi) {
#pragma unroll
    for (int ni = 0; ni < 4; ++ni) {
#pragma unroll
      for (int r = 0; r < 4; ++r) {
        const int row = crow + mi * 16 + r;
        const int col = ccol + ni * 16;
        const size_t idx = (size_t)row * DIM + col;
        if (MODE == 0) {
          ((__bf16*)outp)[idx] = (__bf16)(acc[mi][ni][r] + bvv[ni]);
        } else if (MODE == 3) {
          ((float*)outp)[idx] = acc[mi][ni][r] + bvv[ni] + xres[idx];
        } else if (MODE == 5) {
          ((__bf16*)outp)[idx] = (__bf16)(acc[mi][ni][r] * ms);
        } else {  // MODE 7
          float v = basep[(size_t)(row & (SEQ - 1)) * DIM + col] + acc[mi][ni][r] + bvv[ni];
          v -= 6.2831853f * rintf(v * 0.15915494f);   // wrap to [-pi,pi]
          ((__bf16*)outp)[idx] = (__bf16)v;
        }
      }
    }
  }
}

// Per chunk (64 rows) x full D: in-register cumsum of value*e^{i*kph},
// retrieve with qph, /sqrt(D), per-row LayerNorm, emit bf16 normed.
__global__ __launch_bounds__(256)
void phasor_ln(const __bf16* __restrict__ val, const __bf16* __restrict__ kph,
               const __bf16* __restrict__ qph, const float* __restrict__ g,
               const float* __restrict__ lb, __bf16* __restrict__ nb)
{
  const int t = threadIdx.x;
  const size_t r0 = (size_t)blockIdx.x * CHUNK;
  const int c = t * 4;
  const f32x4 gv  = ((const f32x4*)g)[t];
  const f32x4 lbv = ((const f32x4*)lb)[t];
  __shared__ float red[8];
  float mr[4] = {0.f, 0.f, 0.f, 0.f};
  float mi[4] = {0.f, 0.f, 0.f, 0.f};
  size_t base = r0 * DIM + c;
  f32x4 v  = ld4f(val + base);
  f32x4 kp = ld4f(kph + base);
  f32x4 qp = ld4f(qph + base);
  for (int r = 0; r < CHUNK; ++r) {
    const size_t nbase = base + ((r + 1 < CHUNK) ? DIM : 0);
    f32x4 nv  = ld4f(val + nbase);
    f32x4 nkp = ld4f(kph + nbase);
    f32x4 nqp = ld4f(qph + nbase);
    float ret[4];
    float s = 0.f, q = 0.f;
#pragma unroll
    for (int j = 0; j < 4; ++j) {
      float sk, ck, sq, cq;
      __sincosf(kp[j], &sk, &ck);
      mr[j] += v[j] * ck;
      mi[j] += v[j] * sk;
      __sincosf(qp[j], &sq, &cq);
      ret[j] = (mr[j] * cq + mi[j] * sq) * 0.03125f;   // 1/sqrt(1024)
      s += ret[j];
      q += ret[j] * ret[j];
    }
#pragma unroll
    for (int off = 32; off > 0; off >>= 1) {
      s += __shfl_down(s, off);
      q += __shfl_down(q, off);
    }
    if ((t & 63) == 0) { red[t >> 6] = s; red[4 + (t >> 6)] = q; }
    __syncthreads();
    const float mu   = (red[0] + red[1] + red[2] + red[3]) * (1.0f / DIM);
    const float varr = (red[4] + red[5] + red[6] + red[7]) * (1.0f / DIM) - mu * mu;
    const float rinv = rsqrtf(varr + 1e-5f);
    bf16x4 o;
#pragma unroll
    for (int j = 0; j < 4; ++j) o[j] = (__bf16)((ret[j] - mu) * rinv * gv[j] + lbv[j]);
    *(bf16x4*)(nb + base) = o;
    __syncthreads();
    base += DIM;
    v = nv; kp = nkp; qp = nqp;
  }
}

// fp32 -> bf16, 4/thread
__global__ void f2b_kernel(const float* __restrict__ in, __bf16* __restrict__ out, int n4) {
  int i = blockIdx.x * 256 + threadIdx.x;
  if (i >= n4) return;
  f32x4 vv = ((const f32x4*)in)[i];
  bf16x4 o;
#pragma unroll
  for (int j = 0; j < 4; ++j) o[j] = (__bf16)vv[j];
  ((bf16x4*)out)[i] = o;
}

// Wt[n][k] = (bf16) W[k][n]
__global__ void transpose_f2b(const float* __restrict__ W, __bf16* __restrict__ Wt) {
  __shared__ float tle[32][33];
  const int tx = threadIdx.x, ty = threadIdx.y;
  const int bx = blockIdx.x * 32, by = blockIdx.y * 32;
  for (int i = ty; i < 32; i += 8) tle[i][tx] = W[(size_t)(by + i) * DIM + bx + tx];
  __syncthreads();
  for (int i = ty; i < 32; i += 8) Wt[(size_t)(bx + i) * DIM + by + tx] = (__bf16)tle[tx][i];
}

// out[n] = (sum_k bsrc[k]*W[k][n] + badd[n]) * ms[0]   (combined bias, f32)
__global__ void biascomb_kernel(const float* __restrict__ bsrc, const float* __restrict__ W,
                                const float* __restrict__ badd, const float* __restrict__ ms,
                                float* __restrict__ out)
{
  const int n = blockIdx.x * 256 + threadIdx.x;
  float s = 0.f;
  for (int k = 0; k < DIM; ++k) s += bsrc[k] * W[(size_t)k * DIM + n];
  out[n] = (s + badd[n]) * ms[0];
}

// diagnostic fallback: out = x (absmax ~6.5 signals "workspace too small")
__global__ void copyx_kernel(const float* __restrict__ x, float* __restrict__ out, int n4) {
  int i = blockIdx.x * 256 + threadIdx.x;
  if (i >= n4) return;
  ((f32x4*)out)[i] = ((const f32x4*)x)[i];
}

extern "C" void kernel_launch(void* const* d_in, const int* in_sizes, int n_in,
                              void* d_out, int out_size, void* d_ws, size_t ws_size,
                              hipStream_t stream)
{
  (void)in_sizes; (void)n_in; (void)out_size;
  const float* x     = (const float*)d_in[0];
  const float* basep = (const float*)d_in[1];
  const float* Wk    = (const float*)d_in[2];
  const float* bk    = (const float*)d_in[3];
  const float* Wv    = (const float*)d_in[4];
  const float* bv    = (const float*)d_in[5];
  const float* Wq    = (const float*)d_in[6];
  const float* bq    = (const float*)d_in[7];
  const float* Wkm   = (const float*)d_in[8];
  const float* bkm   = (const float*)d_in[9];
  const float* Wqm   = (const float*)d_in[10];
  const float* bqm   = (const float*)d_in[11];
  const float* msc   = (const float*)d_in[12];
  const float* lng   = (const float*)d_in[13];
  const float* lnb   = (const float*)d_in[14];
  const float* Wo    = (const float*)d_in[15];
  const float* bo    = (const float*)d_in[16];

  char* ws = (char*)d_ws;
  const size_t MB = 1ull << 20;
  if (ws_size < 146 * MB) {
    copyx_kernel<<<MROWS * DIM / 4 / 256, 256, 0, stream>>>(x, (float*)d_out, MROWS * DIM / 4);
    return;
  }

  // layout (144 MB + 8 KB):
  __bf16* xb    = (__bf16*)ws;              // [0,32)   x bf16; nbuf aliases after phases
  __bf16* valb  = (__bf16*)(ws +  32 * MB); // [32,64)  value bf16
  __bf16* kphb  = (__bf16*)(ws +  64 * MB); // [64,96)  key_phase bf16 (wrapped)
  __bf16* qphb  = (__bf16*)(ws +  96 * MB); // [96,128) query_phase bf16 (wrapped)
  __bf16* WvT   = (__bf16*)(ws + 128 * MB); // [128,130)
  __bf16* WoT   = (__bf16*)(ws + 130 * MB); // [130,132)
  __bf16* WkmP  = (__bf16*)(ws + 132 * MB); // [132,134) (Wk@Wkm)^T * ms, bf16
  __bf16* WqmP  = (__bf16*)(ws + 134 * MB); // [134,136)
  __bf16* TWkm  = (__bf16*)(ws + 136 * MB); // [136,138) tmp: Wkm^T
  __bf16* BWk   = (__bf16*)(ws + 138 * MB); // [138,140) tmp: bf16(Wk)
  __bf16* TWqm  = (__bf16*)(ws + 140 * MB); // [140,142) tmp: Wqm^T
  __bf16* BWq   = (__bf16*)(ws + 142 * MB); // [142,144) tmp: bf16(Wq)
  float*  bkmP  = (float*)(ws + 144 * MB);          // 4 KB
  float*  bqmP  = (float*)(ws + 144 * MB + 4096);   // 4 KB
  __bf16* nbuf  = xb;

  // --- preps ---
  f2b_kernel<<<MROWS * DIM / 4 / 256, 256, 0, stream>>>(x, xb, MROWS * DIM / 4);
  dim3 tg(32, 32), tb(32, 8);
  transpose_f2b<<<tg, tb, 0, stream>>>(Wv,  WvT);
  transpose_f2b<<<tg, tb, 0, stream>>>(Wo,  WoT);
  transpose_f2b<<<tg, tb, 0, stream>>>(Wkm, TWkm);
  transpose_f2b<<<tg, tb, 0, stream>>>(Wqm, TWqm);
  f2b_kernel<<<DIM * DIM / 4 / 256, 256, 0, stream>>>(Wk, BWk, DIM * DIM / 4);
  f2b_kernel<<<DIM * DIM / 4 / 256, 256, 0, stream>>>(Wq, BWq, DIM * DIM / 4);

  // weight combines: WkmP[n][k] = ((Wk@Wkm)[k][n]) * ms   (Bt-format for phase GEMM)
  dim3 gs(DIM / 128, DIM / 128);   // 8x8
  gemm_bt<5, false><<<gs, 256, 0, stream>>>(TWkm, BWk, nullptr, WkmP, nullptr, msc, nullptr);
  gemm_bt<5, false><<<gs, 256, 0, stream>>>(TWqm, BWq, nullptr, WqmP, nullptr, msc, nullptr);
  biascomb_kernel<<<DIM / 256, 256, 0, stream>>>(bk, Wkm, bkm, msc, bkmP);
  biascomb_kernel<<<DIM / 256, 256, 0, stream>>>(bq, Wqm, bqm, msc, bqmP);

  // --- main pipeline: 4 big GEMMs + phasor ---
  dim3 gg(DIM / 128, MROWS / 128);   // (8,128)
  gemm_bt<0, true><<<gg, 256, 0, stream>>>(xb, WvT,  bv,   valb, nullptr, nullptr, nullptr);
  gemm_bt<7, true><<<gg, 256, 0, stream>>>(xb, WkmP, bkmP, kphb, basep,   nullptr, nullptr);
  gemm_bt<7, true><<<gg, 256, 0, stream>>>(xb, WqmP, bqmP, qphb, basep,   nullptr, nullptr);
  // xb dead from here (nbuf aliases it)
  phasor_ln<<<NCHUNKBLKS, 256, 0, stream>>>(valb, kphb, qphb, lng, lnb, nbuf);
  gemm_bt<3, true><<<gg, 256, 0, stream>>>(nbuf, WoT, bo, d_out, nullptr, nullptr, x);
}

// Round 5
// 365.993 us; speedup vs baseline: 1.0882x; 1.0882x over previous
//
#include <hip/hip_runtime.h>

#define DIM 1024
#define SEQ 4096
#define MROWS 16384      // BATCH * SEQ
#define CHUNK 64
#define NCHUNKBLKS 256   // MROWS / CHUNK

typedef float  f32x4  __attribute__((ext_vector_type(4)));
typedef __bf16 bf16x8 __attribute__((ext_vector_type(8)));
typedef __bf16 bf16x4 __attribute__((ext_vector_type(4)));

// async global->LDS, 16B per lane. LDS dest is wave-uniform base + lane*16.
__device__ __forceinline__ void gld16(const void* g, void* l) {
  __builtin_amdgcn_global_load_lds((__attribute__((address_space(1))) void*)g,
                                   (__attribute__((address_space(3))) void*)l,
                                   16, 0, 0);
}

__device__ __forceinline__ f32x4 ld4f(const __bf16* p) {
  bf16x4 v = *(const bf16x4*)p;
  f32x4 r;
#pragma unroll
  for (int j = 0; j < 4; ++j) r[j] = (float)v[j];
  return r;
}

// Single-buffer K-loop (m97 structure; dbuf proven neutral — __syncthreads
// drains vmcnt(0) anyway). T2 both-sides XOR swizzle -> 0 bank conflicts.
#define KLOOP(As_, Bs_, Ag_, Bg_, AsL_, BsL_)                                    \
  for (int kt = 0; kt < DIM / 32; ++kt) {                                        \
    const __bf16* a_ = Ag_ + kt * 32;                                            \
    const __bf16* b_ = Bg_ + kt * 32;                                            \
    gld16(a_,            AsL_);                                                  \
    gld16(a_ + 64 * DIM, AsL_ + 4096);                                           \
    gld16(b_,            BsL_);                                                  \
    gld16(b_ + 64 * DIM, BsL_ + 4096);                                           \
    __syncthreads();                                                             \
    const bf16x8* Av_ = (const bf16x8*)(As_);                                    \
    const bf16x8* Bv_ = (const bf16x8*)(Bs_);                                    \
    bf16x8 af[4], bfv[4];                                                        \
    _Pragma("unroll") for (int i = 0; i < 4; ++i) af[i]  = Av_[(ar + i*16)*4 + aidx]; \
    _Pragma("unroll") for (int i = 0; i < 4; ++i) bfv[i] = Bv_[(br + i*16)*4 + bidx]; \
    _Pragma("unroll") for (int mi = 0; mi < 4; ++mi)                             \
      _Pragma("unroll") for (int ni = 0; ni < 4; ++ni)                           \
        acc[mi][ni] = __builtin_amdgcn_mfma_f32_16x16x32_bf16(af[mi], bfv[ni], acc[mi][ni], 0, 0, 0); \
    __syncthreads();                                                             \
  }

// Common per-thread geometry (4 waves, 128x128 tile, 64B LDS rows).
#define GEMM_PROLOG(A_, B_)                                                      \
  const int tid  = threadIdx.x;                                                  \
  const int lane = tid & 63;                                                     \
  const int widx = tid >> 6;                                                     \
  const int wr   = widx >> 1, wc = widx & 1;                                     \
  const int kc = ((lane & 3) ^ ((lane >> 3) & 3)) * 8;                           \
  const __bf16* Ag = (A_) + (size_t)(row0 + widx * 16 + (lane >> 2)) * DIM + kc; \
  const __bf16* Bg = (B_) + (size_t)(col0 + widx * 16 + (lane >> 2)) * DIM + kc; \
  char* AsL = (char*)As + widx * 1024;                                           \
  char* BsL = (char*)Bs + widx * 1024;                                           \
  f32x4 acc[4][4] = {};                                                          \
  const int ar = wr * 64 + (lane & 15);                                          \
  const int br = wc * 64 + (lane & 15);                                          \
  const int kg = lane >> 4;                                                      \
  const int aidx = kg ^ ((ar >> 1) & 3);                                         \
  const int bidx = kg ^ ((br >> 1) & 3);

// MODE 3: out f32  = acc + bias + xres   (final residual GEMM)
// MODE 5: out bf16 = acc * ms            (weight combine; batched via blockIdx.z)
// SWZ=1: XCD row-band remap for grid (8,128).
template <int MODE, int SWZ>
__global__ __launch_bounds__(256, 2)
void gemm_bt(const __bf16* __restrict__ A, const __bf16* __restrict__ Bt,
             const float* __restrict__ bias, void* __restrict__ outp,
             const float* __restrict__ mscp, const float* __restrict__ xres,
             const __bf16* __restrict__ A2, const __bf16* __restrict__ Bt2,
             void* __restrict__ out2)
{
  __shared__ __bf16 As[128 * 32];
  __shared__ __bf16 Bs[128 * 32];
  if (MODE == 5 && blockIdx.z == 1) { A = A2; Bt = Bt2; outp = out2; }

  int row_t, col_t;
  if (SWZ == 1) {
    const int b = blockIdx.y * 8 + blockIdx.x;   // grid (8,128)
    const int xcd = b & 7, slot = b >> 3;
    col_t = slot & 7;
    row_t = (xcd << 4) | (slot >> 3);
  } else {
    row_t = blockIdx.y; col_t = blockIdx.x;
  }
  const int row0 = row_t * 128, col0 = col_t * 128;

  GEMM_PROLOG(A, Bt)
  KLOOP(As, Bs, Ag, Bg, AsL, BsL)

  // C/D frag mapping (HW-verified): col = lane&15, row = (lane>>4)*4 + r
  const int ccol = col0 + wc * 64 + (lane & 15);
  const int crow = row0 + wr * 64 + kg * 4;
  float bvv[4];
  if (MODE != 5) {
#pragma unroll
    for (int ni = 0; ni < 4; ++ni) bvv[ni] = bias[ccol + ni * 16];
  }
  float ms = 0.f;
  if (MODE == 5) ms = mscp[0];
#pragma unroll
  for (int mi = 0; mi < 4; ++mi)
#pragma unroll
    for (int ni = 0; ni < 4; ++ni)
#pragma unroll
      for (int r = 0; r < 4; ++r) {
        const int row = crow + mi * 16 + r;
        const int col = ccol + ni * 16;
        const size_t idx = (size_t)row * DIM + col;
        if (MODE == 3) {
          ((float*)outp)[idx] = acc[mi][ni][r] + bvv[ni] + xres[idx];
        } else {  // MODE 5
          ((__bf16*)outp)[idx] = (__bf16)(acc[mi][ni][r] * ms);
        }
      }
}

// Fused x-GEMM: C[16384, 3072] = xb @ Ball^T, Ball rows = [WvT | WkmP | WqmP].
// Band 0 -> valb bf16 (acc+bias); bands 1,2 -> wrapped phase bf16 into kphb/qphb.
// Grid (24,128); XCD band swizzle: each XCD owns 16 row-panels x 24 col-tiles
// (A band 4 MB ~ its L2).
__global__ __launch_bounds__(256, 2)
void gemm3(const __bf16* __restrict__ A, const __bf16* __restrict__ Ball,
           const float* __restrict__ biasAll, const float* __restrict__ basep,
           __bf16* __restrict__ valb, __bf16* __restrict__ kphb,
           __bf16* __restrict__ qphb)
{
  __shared__ __bf16 As[128 * 32];
  __shared__ __bf16 Bs[128 * 32];
  const int b = blockIdx.y * 24 + blockIdx.x;   // linear id, grid (24,128)
  const int xcd = b & 7, p = b >> 3;            // (xcd,p) bijective
  const int col_t = p % 24;
  const int row_t = (xcd << 4) + p / 24;
  const int row0 = row_t * 128, col0 = col_t * 128;

  GEMM_PROLOG(A, Ball)
  KLOOP(As, Bs, Ag, Bg, AsL, BsL)

  const int band = col_t >> 3;                  // 0:V 1:kph 2:qph
  const int ccol = col0 + wc * 64 + (lane & 15);
  const int lcol0 = ccol & 1023;                // col within the 1024-band
  const int crow = row0 + wr * 64 + kg * 4;
  float bvv[4];
#pragma unroll
  for (int ni = 0; ni < 4; ++ni) bvv[ni] = biasAll[ccol + ni * 16];
  __bf16* outb = (band == 0) ? valb : (band == 1) ? kphb : qphb;
#pragma unroll
  for (int mi = 0; mi < 4; ++mi)
#pragma unroll
    for (int ni = 0; ni < 4; ++ni)
#pragma unroll
      for (int r = 0; r < 4; ++r) {
        const int row = crow + mi * 16 + r;
        const int lcol = lcol0 + ni * 16;
        const size_t idx = (size_t)row * DIM + lcol;
        float v = acc[mi][ni][r] + bvv[ni];
        if (band != 0) {
          v += basep[(size_t)(row & (SEQ - 1)) * DIM + lcol];
          v -= 6.2831853f * rintf(v * 0.15915494f);   // wrap to [-pi,pi]
        }
        outb[idx] = (__bf16)v;
      }
}

// Per chunk (64 rows) x full D: in-register cumsum of value*e^{i*kph},
// retrieve with qph, /sqrt(D), per-row LayerNorm, emit bf16 normed.
__global__ __launch_bounds__(256)
void phasor_ln(const __bf16* __restrict__ val, const __bf16* __restrict__ kph,
               const __bf16* __restrict__ qph, const float* __restrict__ g,
               const float* __restrict__ lb, __bf16* __restrict__ nb)
{
  const int t = threadIdx.x;
  const size_t r0 = (size_t)blockIdx.x * CHUNK;
  const int c = t * 4;
  const f32x4 gv  = ((const f32x4*)g)[t];
  const f32x4 lbv = ((const f32x4*)lb)[t];
  __shared__ float red[8];
  float mr[4] = {0.f, 0.f, 0.f, 0.f};
  float mi[4] = {0.f, 0.f, 0.f, 0.f};
  size_t base = r0 * DIM + c;
  f32x4 v  = ld4f(val + base);
  f32x4 kp = ld4f(kph + base);
  f32x4 qp = ld4f(qph + base);
  for (int r = 0; r < CHUNK; ++r) {
    const size_t nbase = base + ((r + 1 < CHUNK) ? DIM : 0);
    f32x4 nv  = ld4f(val + nbase);
    f32x4 nkp = ld4f(kph + nbase);
    f32x4 nqp = ld4f(qph + nbase);
    float ret[4];
    float s = 0.f, q = 0.f;
#pragma unroll
    for (int j = 0; j < 4; ++j) {
      float sk, ck, sq, cq;
      __sincosf(kp[j], &sk, &ck);
      mr[j] += v[j] * ck;
      mi[j] += v[j] * sk;
      __sincosf(qp[j], &sq, &cq);
      ret[j] = (mr[j] * cq + mi[j] * sq) * 0.03125f;   // 1/sqrt(1024)
      s += ret[j];
      q += ret[j] * ret[j];
    }
#pragma unroll
    for (int off = 32; off > 0; off >>= 1) {
      s += __shfl_down(s, off);
      q += __shfl_down(q, off);
    }
    if ((t & 63) == 0) { red[t >> 6] = s; red[4 + (t >> 6)] = q; }
    __syncthreads();
    const float mu   = (red[0] + red[1] + red[2] + red[3]) * (1.0f / DIM);
    const float varr = (red[4] + red[5] + red[6] + red[7]) * (1.0f / DIM) - mu * mu;
    const float rinv = rsqrtf(varr + 1e-5f);
    bf16x4 o;
#pragma unroll
    for (int j = 0; j < 4; ++j) o[j] = (__bf16)((ret[j] - mu) * rinv * gv[j] + lbv[j]);
    *(bf16x4*)(nb + base) = o;
    __syncthreads();
    base += DIM;
    v = nv; kp = nkp; qp = nqp;
  }
}

// fp32 -> bf16, 4/thread
__global__ void f2b_kernel(const float* __restrict__ in, __bf16* __restrict__ out, int n4) {
  int i = blockIdx.x * 256 + threadIdx.x;
  if (i >= n4) return;
  f32x4 vv = ((const f32x4*)in)[i];
  bf16x4 o;
#pragma unroll
  for (int j = 0; j < 4; ++j) o[j] = (__bf16)vv[j];
  ((bf16x4*)out)[i] = o;
}

// fp32 -> bf16, two tensors batched on blockIdx.y
__global__ void f2b2_kernel(const float* __restrict__ i0, __bf16* __restrict__ o0,
                            const float* __restrict__ i1, __bf16* __restrict__ o1, int n4) {
  int i = blockIdx.x * 256 + threadIdx.x;
  if (i >= n4) return;
  const float* in = blockIdx.y ? i1 : i0;
  __bf16* out = blockIdx.y ? o1 : o0;
  f32x4 vv = ((const f32x4*)in)[i];
  bf16x4 o;
#pragma unroll
  for (int j = 0; j < 4; ++j) o[j] = (__bf16)vv[j];
  ((bf16x4*)out)[i] = o;
}

// Wt[n][k] = (bf16) W[k][n], 4 matrices batched on blockIdx.z
__global__ void transpose_f2b4(const float* __restrict__ s0, __bf16* __restrict__ d0,
                               const float* __restrict__ s1, __bf16* __restrict__ d1,
                               const float* __restrict__ s2, __bf16* __restrict__ d2,
                               const float* __restrict__ s3, __bf16* __restrict__ d3) {
  __shared__ float tle[32][33];
  const float* W; __bf16* Wt;
  switch (blockIdx.z) {
    case 0: W = s0; Wt = d0; break;
    case 1: W = s1; Wt = d1; break;
    case 2: W = s2; Wt = d2; break;
    default: W = s3; Wt = d3; break;
  }
  const int tx = threadIdx.x, ty = threadIdx.y;
  const int bx = blockIdx.x * 32, by = blockIdx.y * 32;
  for (int i = ty; i < 32; i += 8) tle[i][tx] = W[(size_t)(by + i) * DIM + bx + tx];
  __syncthreads();
  for (int i = ty; i < 32; i += 8) Wt[(size_t)(bx + i) * DIM + by + tx] = (__bf16)tle[tx][i];
}

// biasAll[0:1024)=bv; [1024:2048)=(bk@Wkm+bkm)*ms; [2048:3072)=(bq@Wqm+bqm)*ms
// grid (4,3) x 256
__global__ void biascomb3(const float* __restrict__ bk, const float* __restrict__ Wkm,
                          const float* __restrict__ bkm, const float* __restrict__ bq,
                          const float* __restrict__ Wqm, const float* __restrict__ bqm,
                          const float* __restrict__ bv, const float* __restrict__ ms,
                          float* __restrict__ biasAll)
{
  const int n = blockIdx.x * 256 + threadIdx.x;
  const int which = blockIdx.y;
  if (which == 2) { biasAll[n] = bv[n]; return; }
  const float* bs = which ? bq : bk;
  const float* W  = which ? Wqm : Wkm;
  const float* ba = which ? bqm : bkm;
  float s = 0.f;
  for (int k = 0; k < DIM; ++k) s += bs[k] * W[(size_t)k * DIM + n];
  biasAll[1024 + which * 1024 + n] = (s + ba[n]) * ms[0];
}

// diagnostic fallback: out = x (absmax ~6.5 signals "workspace too small")
__global__ void copyx_kernel(const float* __restrict__ x, float* __restrict__ out, int n4) {
  int i = blockIdx.x * 256 + threadIdx.x;
  if (i >= n4) return;
  ((f32x4*)out)[i] = ((const f32x4*)x)[i];
}

extern "C" void kernel_launch(void* const* d_in, const int* in_sizes, int n_in,
                              void* d_out, int out_size, void* d_ws, size_t ws_size,
                              hipStream_t stream)
{
  (void)in_sizes; (void)n_in; (void)out_size;
  const float* x     = (const float*)d_in[0];
  const float* basep = (const float*)d_in[1];
  const float* Wk    = (const float*)d_in[2];
  const float* bk    = (const float*)d_in[3];
  const float* Wv    = (const float*)d_in[4];
  const float* bv    = (const float*)d_in[5];
  const float* Wq    = (const float*)d_in[6];
  const float* bq    = (const float*)d_in[7];
  const float* Wkm   = (const float*)d_in[8];
  const float* bkm   = (const float*)d_in[9];
  const float* Wqm   = (const float*)d_in[10];
  const float* bqm   = (const float*)d_in[11];
  const float* msc   = (const float*)d_in[12];
  const float* lng   = (const float*)d_in[13];
  const float* lnb   = (const float*)d_in[14];
  const float* Wo    = (const float*)d_in[15];
  const float* bo    = (const float*)d_in[16];

  char* ws = (char*)d_ws;
  const size_t MB = 1ull << 20;
  if (ws_size < 146 * MB) {
    copyx_kernel<<<MROWS * DIM / 4 / 256, 256, 0, stream>>>(x, (float*)d_out, MROWS * DIM / 4);
    return;
  }

  // layout (144 MB + 12 KB):
  __bf16* xb     = (__bf16*)ws;              // [0,32)   x bf16; nbuf aliases it after use
  __bf16* valb   = (__bf16*)(ws +  32 * MB); // [32,64)
  __bf16* kphb   = (__bf16*)(ws +  64 * MB); // [64,96)
  __bf16* qphb   = (__bf16*)(ws +  96 * MB); // [96,128)
  __bf16* Ball   = (__bf16*)(ws + 128 * MB); // [128,134) rows: WvT | WkmP | WqmP
  __bf16* WoT    = (__bf16*)(ws + 134 * MB); // [134,136)
  __bf16* TWkm   = (__bf16*)(ws + 136 * MB); // [136,138)
  __bf16* BWk    = (__bf16*)(ws + 138 * MB); // [138,140)
  __bf16* TWqm   = (__bf16*)(ws + 140 * MB); // [140,142)
  __bf16* BWq    = (__bf16*)(ws + 142 * MB); // [142,144)
  float*  biasAll= (float*)(ws + 144 * MB);  // 12 KB (bv | key-combined | query-combined)
  __bf16* nbuf   = xb;

  // --- preps (batched) ---
  f2b_kernel<<<MROWS * DIM / 4 / 256, 256, 0, stream>>>(x, xb, MROWS * DIM / 4);
  dim3 tg(32, 32, 4), tb(32, 8);
  transpose_f2b4<<<tg, tb, 0, stream>>>(Wv, Ball, Wo, WoT, Wkm, TWkm, Wqm, TWqm);
  f2b2_kernel<<<dim3(DIM * DIM / 4 / 256, 2), 256, 0, stream>>>(Wk, BWk, Wq, BWq, DIM * DIM / 4);
  // weight combines -> Ball rows [1024,2048) and [2048,3072)
  gemm_bt<5, 0><<<dim3(8, 8, 2), 256, 0, stream>>>(
      TWkm, BWk, nullptr, Ball + (size_t)1024 * DIM, msc, nullptr,
      TWqm, BWq, Ball + (size_t)2048 * DIM);
  biascomb3<<<dim3(4, 3), 256, 0, stream>>>(bk, Wkm, bkm, bq, Wqm, bqm, bv, msc, biasAll);

  // --- main pipeline ---
  gemm3<<<dim3(24, 128), 256, 0, stream>>>(xb, Ball, biasAll, basep, valb, kphb, qphb);
  phasor_ln<<<NCHUNKBLKS, 256, 0, stream>>>(valb, kphb, qphb, lng, lnb, nbuf);
  gemm_bt<3, 1><<<dim3(8, 128), 256, 0, stream>>>(
      nbuf, WoT, bo, d_out, nullptr, x, nullptr, nullptr, nullptr);
}

// Round 6
// 288.942 us; speedup vs baseline: 1.3784x; 1.2667x over previous
//
#include <hip/hip_runtime.h>

#define DIM 1024
#define SEQ 4096
#define MROWS 16384      // BATCH * SEQ
#define CHUNK 64
#define NCHUNKBLKS 256   // MROWS / CHUNK

typedef float  f32x4  __attribute__((ext_vector_type(4)));
typedef __bf16 bf16x8 __attribute__((ext_vector_type(8)));
typedef __bf16 bf16x4 __attribute__((ext_vector_type(4)));

// async global->LDS, 16B per lane. LDS dest is wave-uniform base + lane*16.
__device__ __forceinline__ void gld16(const void* g, void* l) {
  __builtin_amdgcn_global_load_lds((__attribute__((address_space(1))) void*)g,
                                   (__attribute__((address_space(3))) void*)l,
                                   16, 0, 0);
}

__device__ __forceinline__ f32x4 ld4f(const __bf16* p) {
  bf16x4 v = *(const bf16x4*)p;
  f32x4 r;
#pragma unroll
  for (int j = 0; j < 4; ++j) r[j] = (float)v[j];
  return r;
}

// BK=64 K-loop, single-buffer (dbuf proven neutral: __syncthreads drains vmcnt).
// LDS rows are 128 B (8 x 16B chunks). Both-sides XOR swizzle:
// physical chunk = logical chunk ^ (row&7); staging pre-permutes the GLOBAL
// source chunk identically (global_load_lds writes linearly). Lanes 0-15 of a
// quarter-group hit 8 distinct chunk slots x2 -> 2-way aliasing (free, m136).
#define KLOOP64(As_, Bs_, Ag_, Bg_, AsL_, BsL_)                                  \
  for (int kt = 0; kt < DIM / 64; ++kt) {                                        \
    const __bf16* a_ = Ag_ + kt * 64;                                            \
    const __bf16* b_ = Bg_ + kt * 64;                                            \
    _Pragma("unroll") for (int i = 0; i < 4; ++i) {                              \
      gld16(a_ + i * 32 * DIM, AsL_ + i * 4096);                                 \
      gld16(b_ + i * 32 * DIM, BsL_ + i * 4096);                                 \
    }                                                                            \
    __syncthreads();                                                             \
    const bf16x8* Av_ = (const bf16x8*)(As_);                                    \
    const bf16x8* Bv_ = (const bf16x8*)(Bs_);                                    \
    _Pragma("unroll") for (int kk = 0; kk < 2; ++kk) {                           \
      bf16x8 af[4], bfv[4];                                                      \
      const int pc = (kk * 4 + kg) ^ (lane & 7);                                 \
      _Pragma("unroll") for (int i = 0; i < 4; ++i) af[i]  = Av_[(ar + i*16)*8 + pc]; \
      _Pragma("unroll") for (int i = 0; i < 4; ++i) bfv[i] = Bv_[(br + i*16)*8 + pc]; \
      _Pragma("unroll") for (int mi = 0; mi < 4; ++mi)                           \
        _Pragma("unroll") for (int ni = 0; ni < 4; ++ni)                         \
          acc[mi][ni] = __builtin_amdgcn_mfma_f32_16x16x32_bf16(af[mi], bfv[ni], acc[mi][ni], 0, 0, 0); \
    }                                                                            \
    __syncthreads();                                                             \
  }

// Common per-thread geometry (4 waves, 128x128 tile, BK=64, 128B LDS rows).
// staging: wave w, issue i, lane l covers LDS row w*8 + i*32 + (l>>3),
// chunk l&7; pre-swizzled global source chunk = (l&7) ^ ((l>>3)&7).
#define GEMM_PROLOG64(A_, B_)                                                    \
  const int tid  = threadIdx.x;                                                  \
  const int lane = tid & 63;                                                     \
  const int widx = tid >> 6;                                                     \
  const int wr   = widx >> 1, wc = widx & 1;                                     \
  const int kc = ((lane & 7) ^ ((lane >> 3) & 7)) * 8;                           \
  const __bf16* Ag = (A_) + (size_t)(row0 + widx * 8 + (lane >> 3)) * DIM + kc;  \
  const __bf16* Bg = (B_) + (size_t)(col0 + widx * 8 + (lane >> 3)) * DIM + kc;  \
  char* AsL = (char*)As + widx * 1024;                                           \
  char* BsL = (char*)Bs + widx * 1024;                                           \
  f32x4 acc[4][4] = {};                                                          \
  const int ar = wr * 64 + (lane & 15);                                          \
  const int br = wc * 64 + (lane & 15);                                          \
  const int kg = lane >> 4;

// MODE 3: out f32  = acc + bias + xres   (final residual GEMM)
// MODE 5: out bf16 = acc * ms            (weight combine; batched via blockIdx.z)
// SWZ=1: XCD row-band remap for grid (8,128).
template <int MODE, int SWZ>
__global__ __launch_bounds__(256, 2)
void gemm_bt(const __bf16* __restrict__ A, const __bf16* __restrict__ Bt,
             const float* __restrict__ bias, void* __restrict__ outp,
             const float* __restrict__ mscp, const float* __restrict__ xres,
             const __bf16* __restrict__ A2, const __bf16* __restrict__ Bt2,
             void* __restrict__ out2)
{
  __shared__ __bf16 As[128 * 64];   // 16 KB
  __shared__ __bf16 Bs[128 * 64];
  if (MODE == 5 && blockIdx.z == 1) { A = A2; Bt = Bt2; outp = out2; }

  int row_t, col_t;
  if (SWZ == 1) {
    const int b = blockIdx.y * 8 + blockIdx.x;   // grid (8,128)
    const int xcd = b & 7, slot = b >> 3;
    col_t = slot & 7;
    row_t = (xcd << 4) | (slot >> 3);
  } else {
    row_t = blockIdx.y; col_t = blockIdx.x;
  }
  const int row0 = row_t * 128, col0 = col_t * 128;

  GEMM_PROLOG64(A, Bt)
  KLOOP64(As, Bs, Ag, Bg, AsL, BsL)

  // C/D frag mapping (HW-verified): col = lane&15, row = (lane>>4)*4 + r
  const int ccol = col0 + wc * 64 + (lane & 15);
  const int crow = row0 + wr * 64 + kg * 4;
  float bvv[4];
  if (MODE != 5) {
#pragma unroll
    for (int ni = 0; ni < 4; ++ni) bvv[ni] = bias[ccol + ni * 16];
  }
  float ms = 0.f;
  if (MODE == 5) ms = mscp[0];
#pragma unroll
  for (int mi = 0; mi < 4; ++mi)
#pragma unroll
    for (int ni = 0; ni < 4; ++ni)
#pragma unroll
      for (int r = 0; r < 4; ++r) {
        const int row = crow + mi * 16 + r;
        const int col = ccol + ni * 16;
        const size_t idx = (size_t)row * DIM + col;
        if (MODE == 3) {
          ((float*)outp)[idx] = acc[mi][ni][r] + bvv[ni] + xres[idx];
        } else {  // MODE 5
          ((__bf16*)outp)[idx] = (__bf16)(acc[mi][ni][r] * ms);
        }
      }
}

// Fused x-GEMM: C[16384, 3072] = xb @ Ball^T, Ball rows = [WvT | WkmP | WqmP].
// Uniform epilogue: out = bf16(acc + bias). Phase-mod outputs are tiny
// (|v| <~ 0.3): no base add, no wrap here (done in phasor_ln).
// Grid (24,128); XCD band swizzle: each XCD owns 16 row-panels x 24 col-tiles.
__global__ __launch_bounds__(256, 2)
void gemm3(const __bf16* __restrict__ A, const __bf16* __restrict__ Ball,
           const float* __restrict__ biasAll,
           __bf16* __restrict__ valb, __bf16* __restrict__ kphb,
           __bf16* __restrict__ qphb)
{
  __shared__ __bf16 As[128 * 64];
  __shared__ __bf16 Bs[128 * 64];
  const int b = blockIdx.y * 24 + blockIdx.x;   // linear id, grid (24,128)
  const int xcd = b & 7, p = b >> 3;            // (xcd,p) bijective
  const int col_t = p % 24;
  const int row_t = (xcd << 4) + p / 24;
  const int row0 = row_t * 128, col0 = col_t * 128;

  GEMM_PROLOG64(A, Ball)
  KLOOP64(As, Bs, Ag, Bg, AsL, BsL)

  const int band = col_t >> 3;                  // 0:V 1:kph 2:qph
  const int ccol = col0 + wc * 64 + (lane & 15);
  const int lcol0 = ccol & 1023;                // col within the 1024-band
  const int crow = row0 + wr * 64 + kg * 4;
  float bvv[4];
#pragma unroll
  for (int ni = 0; ni < 4; ++ni) bvv[ni] = biasAll[ccol + ni * 16];
  __bf16* outb = (band == 0) ? valb : (band == 1) ? kphb : qphb;
#pragma unroll
  for (int mi = 0; mi < 4; ++mi)
#pragma unroll
    for (int ni = 0; ni < 4; ++ni)
#pragma unroll
      for (int r = 0; r < 4; ++r) {
        const int row = crow + mi * 16 + r;
        const size_t idx = (size_t)row * DIM + lcol0 + ni * 16;
        outb[idx] = (__bf16)(acc[mi][ni][r] + bvv[ni]);
      }
}

// Per chunk (64 rows) x full D: phase = baseb[row&4095] + mod (both bf16);
// in-register cumsum of value*e^{i*kph}, retrieve with qph, /sqrt(D),
// per-row LayerNorm, emit bf16 normed.
__global__ __launch_bounds__(256)
void phasor_ln(const __bf16* __restrict__ val, const __bf16* __restrict__ kph,
               const __bf16* __restrict__ qph, const __bf16* __restrict__ baseb,
               const float* __restrict__ g, const float* __restrict__ lb,
               __bf16* __restrict__ nb)
{
  const int t = threadIdx.x;
  const size_t r0 = (size_t)blockIdx.x * CHUNK;
  const int c = t * 4;
  const f32x4 gv  = ((const f32x4*)g)[t];
  const f32x4 lbv = ((const f32x4*)lb)[t];
  __shared__ float red[8];
  float mr[4] = {0.f, 0.f, 0.f, 0.f};
  float mi[4] = {0.f, 0.f, 0.f, 0.f};
  size_t base = r0 * DIM + c;
  f32x4 v  = ld4f(val + base);
  f32x4 kp = ld4f(kph + base);
  f32x4 qp = ld4f(qph + base);
  f32x4 bp = ld4f(baseb + (size_t)((r0) & (SEQ - 1)) * DIM + c);
  for (int r = 0; r < CHUNK; ++r) {
    const size_t nbase = base + ((r + 1 < CHUNK) ? DIM : 0);
    const int nrow = (int)((r0 + ((r + 1 < CHUNK) ? r + 1 : r)) & (SEQ - 1));
    f32x4 nv  = ld4f(val + nbase);
    f32x4 nkp = ld4f(kph + nbase);
    f32x4 nqp = ld4f(qph + nbase);
    f32x4 nbp = ld4f(baseb + (size_t)nrow * DIM + c);
    float ret[4];
    float s = 0.f, q = 0.f;
#pragma unroll
    for (int j = 0; j < 4; ++j) {
      float sk, ck, sq, cq;
      __sincosf(bp[j] + kp[j], &sk, &ck);
      mr[j] += v[j] * ck;
      mi[j] += v[j] * sk;
      __sincosf(bp[j] + qp[j], &sq, &cq);
      ret[j] = (mr[j] * cq + mi[j] * sq) * 0.03125f;   // 1/sqrt(1024)
      s += ret[j];
      q += ret[j] * ret[j];
    }
#pragma unroll
    for (int off = 32; off > 0; off >>= 1) {
      s += __shfl_down(s, off);
      q += __shfl_down(q, off);
    }
    if ((t & 63) == 0) { red[t >> 6] = s; red[4 + (t >> 6)] = q; }
    __syncthreads();
    const float mu   = (red[0] + red[1] + red[2] + red[3]) * (1.0f / DIM);
    const float varr = (red[4] + red[5] + red[6] + red[7]) * (1.0f / DIM) - mu * mu;
    const float rinv = rsqrtf(varr + 1e-5f);
    bf16x4 o;
#pragma unroll
    for (int j = 0; j < 4; ++j) o[j] = (__bf16)((ret[j] - mu) * rinv * gv[j] + lbv[j]);
    *(bf16x4*)(nb + base) = o;
    __syncthreads();
    base += DIM;
    v = nv; kp = nkp; qp = nqp; bp = nbp;
  }
}

// fp32 -> bf16, 4/thread
__global__ void f2b_kernel(const float* __restrict__ in, __bf16* __restrict__ out, int n4) {
  int i = blockIdx.x * 256 + threadIdx.x;
  if (i >= n4) return;
  f32x4 vv = ((const f32x4*)in)[i];
  bf16x4 o;
#pragma unroll
  for (int j = 0; j < 4; ++j) o[j] = (__bf16)vv[j];
  ((bf16x4*)out)[i] = o;
}

// fp32 -> wrapped-to-[-pi,pi] bf16 (for base_phases)
__global__ void wrapb_kernel(const float* __restrict__ in, __bf16* __restrict__ out, int n4) {
  int i = blockIdx.x * 256 + threadIdx.x;
  if (i >= n4) return;
  f32x4 vv = ((const f32x4*)in)[i];
  bf16x4 o;
#pragma unroll
  for (int j = 0; j < 4; ++j) {
    float v = vv[j];
    v -= 6.2831853f * rintf(v * 0.15915494f);
    o[j] = (__bf16)v;
  }
  ((bf16x4*)out)[i] = o;
}

// fp32 -> bf16, two tensors batched on blockIdx.y
__global__ void f2b2_kernel(const float* __restrict__ i0, __bf16* __restrict__ o0,
                            const float* __restrict__ i1, __bf16* __restrict__ o1, int n4) {
  int i = blockIdx.x * 256 + threadIdx.x;
  if (i >= n4) return;
  const float* in = blockIdx.y ? i1 : i0;
  __bf16* out = blockIdx.y ? o1 : o0;
  f32x4 vv = ((const f32x4*)in)[i];
  bf16x4 o;
#pragma unroll
  for (int j = 0; j < 4; ++j) o[j] = (__bf16)vv[j];
  ((bf16x4*)out)[i] = o;
}

// Wt[n][k] = (bf16) W[k][n], 4 matrices batched on blockIdx.z
__global__ void transpose_f2b4(const float* __restrict__ s0, __bf16* __restrict__ d0,
                               const float* __restrict__ s1, __bf16* __restrict__ d1,
                               const float* __restrict__ s2, __bf16* __restrict__ d2,
                               const float* __restrict__ s3, __bf16* __restrict__ d3) {
  __shared__ float tle[32][33];
  const float* W; __bf16* Wt;
  switch (blockIdx.z) {
    case 0: W = s0; Wt = d0; break;
    case 1: W = s1; Wt = d1; break;
    case 2: W = s2; Wt = d2; break;
    default: W = s3; Wt = d3; break;
  }
  const int tx = threadIdx.x, ty = threadIdx.y;
  const int bx = blockIdx.x * 32, by = blockIdx.y * 32;
  for (int i = ty; i < 32; i += 8) tle[i][tx] = W[(size_t)(by + i) * DIM + bx + tx];
  __syncthreads();
  for (int i = ty; i < 32; i += 8) Wt[(size_t)(bx + i) * DIM + by + tx] = (__bf16)tle[tx][i];
}

// biasAll[0:1024)=bv; [1024:2048)=(bk@Wkm+bkm)*ms; [2048:3072)=(bq@Wqm+bqm)*ms
__global__ void biascomb3(const float* __restrict__ bk, const float* __restrict__ Wkm,
                          const float* __restrict__ bkm, const float* __restrict__ bq,
                          const float* __restrict__ Wqm, const float* __restrict__ bqm,
                          const float* __restrict__ bv, const float* __restrict__ ms,
                          float* __restrict__ biasAll)
{
  const int n = blockIdx.x * 256 + threadIdx.x;
  const int which = blockIdx.y;
  if (which == 2) { biasAll[n] = bv[n]; return; }
  const float* bs = which ? bq : bk;
  const float* W  = which ? Wqm : Wkm;
  const float* ba = which ? bqm : bkm;
  float s = 0.f;
  for (int k = 0; k < DIM; ++k) s += bs[k] * W[(size_t)k * DIM + n];
  biasAll[1024 + which * 1024 + n] = (s + ba[n]) * ms[0];
}

// diagnostic fallback: out = x (absmax ~6.5 signals "workspace too small")
__global__ void copyx_kernel(const float* __restrict__ x, float* __restrict__ out, int n4) {
  int i = blockIdx.x * 256 + threadIdx.x;
  if (i >= n4) return;
  ((f32x4*)out)[i] = ((const f32x4*)x)[i];
}

extern "C" void kernel_launch(void* const* d_in, const int* in_sizes, int n_in,
                              void* d_out, int out_size, void* d_ws, size_t ws_size,
                              hipStream_t stream)
{
  (void)in_sizes; (void)n_in; (void)out_size;
  const float* x     = (const float*)d_in[0];
  const float* basep = (const float*)d_in[1];
  const float* Wk    = (const float*)d_in[2];
  const float* bk    = (const float*)d_in[3];
  const float* Wv    = (const float*)d_in[4];
  const float* bv    = (const float*)d_in[5];
  const float* Wq    = (const float*)d_in[6];
  const float* bq    = (const float*)d_in[7];
  const float* Wkm   = (const float*)d_in[8];
  const float* bkm   = (const float*)d_in[9];
  const float* Wqm   = (const float*)d_in[10];
  const float* bqm   = (const float*)d_in[11];
  const float* msc   = (const float*)d_in[12];
  const float* lng   = (const float*)d_in[13];
  const float* lnb   = (const float*)d_in[14];
  const float* Wo    = (const float*)d_in[15];
  const float* bo    = (const float*)d_in[16];

  char* ws = (char*)d_ws;
  const size_t MB = 1ull << 20;
  if (ws_size < 153 * MB) {   // round-2 pass proved >=176 MB exists
    copyx_kernel<<<MROWS * DIM / 4 / 256, 256, 0, stream>>>(x, (float*)d_out, MROWS * DIM / 4);
    return;
  }

  // layout (152 MB + 12 KB):
  __bf16* xb     = (__bf16*)ws;              // [0,32)   x bf16; nbuf aliases it after use
  __bf16* valb   = (__bf16*)(ws +  32 * MB); // [32,64)
  __bf16* kphb   = (__bf16*)(ws +  64 * MB); // [64,96)  mod-only phase (tiny values)
  __bf16* qphb   = (__bf16*)(ws +  96 * MB); // [96,128)
  __bf16* Ball   = (__bf16*)(ws + 128 * MB); // [128,134) rows: WvT | WkmP | WqmP
  __bf16* WoT    = (__bf16*)(ws + 134 * MB); // [134,136)
  __bf16* TWkm   = (__bf16*)(ws + 136 * MB); // [136,138)
  __bf16* BWk    = (__bf16*)(ws + 138 * MB); // [138,140)
  __bf16* TWqm   = (__bf16*)(ws + 140 * MB); // [140,142)
  __bf16* BWq    = (__bf16*)(ws + 142 * MB); // [142,144)
  __bf16* baseb  = (__bf16*)(ws + 144 * MB); // [144,152) wrapped base_phases bf16
  float*  biasAll= (float*)(ws + 152 * MB);  // 12 KB
  __bf16* nbuf   = xb;

  // --- preps (batched) ---
  f2b_kernel<<<MROWS * DIM / 4 / 256, 256, 0, stream>>>(x, xb, MROWS * DIM / 4);
  wrapb_kernel<<<SEQ * DIM / 4 / 256, 256, 0, stream>>>(basep, baseb, SEQ * DIM / 4);
  dim3 tg(32, 32, 4), tb(32, 8);
  transpose_f2b4<<<tg, tb, 0, stream>>>(Wv, Ball, Wo, WoT, Wkm, TWkm, Wqm, TWqm);
  f2b2_kernel<<<dim3(DIM * DIM / 4 / 256, 2), 256, 0, stream>>>(Wk, BWk, Wq, BWq, DIM * DIM / 4);
  // weight combines -> Ball rows [1024,2048) and [2048,3072)
  gemm_bt<5, 0><<<dim3(8, 8, 2), 256, 0, stream>>>(
      TWkm, BWk, nullptr, Ball + (size_t)1024 * DIM, msc, nullptr,
      TWqm, BWq, Ball + (size_t)2048 * DIM);
  biascomb3<<<dim3(4, 3), 256, 0, stream>>>(bk, Wkm, bkm, bq, Wqm, bqm, bv, msc, biasAll);

  // --- main pipeline ---
  gemm3<<<dim3(24, 128), 256, 0, stream>>>(xb, Ball, biasAll, valb, kphb, qphb);
  phasor_ln<<<NCHUNKBLKS, 256, 0, stream>>>(valb, kphb, qphb, baseb, lng, lnb, nbuf);
  gemm_bt<3, 1><<<dim3(8, 128), 256, 0, stream>>>(
      nbuf, WoT, bo, d_out, nullptr, x, nullptr, nullptr, nullptr);
}

// Round 7
// 264.873 us; speedup vs baseline: 1.5037x; 1.0909x over previous
//
#include <hip/hip_runtime.h>

#define DIM 1024
#define SEQ 4096
#define MROWS 16384      // BATCH * SEQ
#define CHUNK 64
#define NCHUNKBLKS 256   // MROWS / CHUNK

typedef float  f32x4  __attribute__((ext_vector_type(4)));
typedef __bf16 bf16x8 __attribute__((ext_vector_type(8)));
typedef __bf16 bf16x4 __attribute__((ext_vector_type(4)));

// async global->LDS, 16B per lane. LDS dest is wave-uniform base + lane*16.
__device__ __forceinline__ void gld16(const void* g, void* l) {
  __builtin_amdgcn_global_load_lds((__attribute__((address_space(1))) void*)g,
                                   (__attribute__((address_space(3))) void*)l,
                                   16, 0, 0);
}

__device__ __forceinline__ f32x4 ld4f(const __bf16* p) {
  bf16x4 v = *(const bf16x4*)p;
  f32x4 r;
#pragma unroll
  for (int j = 0; j < 4; ++j) r[j] = (float)v[j];
  return r;
}

// BK=64 K-loop, single-buffer (dbuf proven neutral: __syncthreads drains vmcnt).
// LDS rows are 128 B (8 x 16B chunks). Both-sides XOR swizzle:
// physical chunk = logical chunk ^ (row&7); staging pre-permutes the GLOBAL
// source chunk identically (global_load_lds writes linearly). 2-way aliasing only.
#define KLOOP64(As_, Bs_, Ag_, Bg_, AsL_, BsL_)                                  \
  for (int kt = 0; kt < DIM / 64; ++kt) {                                        \
    const __bf16* a_ = Ag_ + kt * 64;                                            \
    const __bf16* b_ = Bg_ + kt * 64;                                            \
    _Pragma("unroll") for (int i = 0; i < 4; ++i) {                              \
      gld16(a_ + i * 32 * DIM, AsL_ + i * 4096);                                 \
      gld16(b_ + i * 32 * DIM, BsL_ + i * 4096);                                 \
    }                                                                            \
    __syncthreads();                                                             \
    const bf16x8* Av_ = (const bf16x8*)(As_);                                    \
    const bf16x8* Bv_ = (const bf16x8*)(Bs_);                                    \
    _Pragma("unroll") for (int kk = 0; kk < 2; ++kk) {                           \
      bf16x8 af[4], bfv[4];                                                      \
      const int pc = (kk * 4 + kg) ^ (lane & 7);                                 \
      _Pragma("unroll") for (int i = 0; i < 4; ++i) af[i]  = Av_[(ar + i*16)*8 + pc]; \
      _Pragma("unroll") for (int i = 0; i < 4; ++i) bfv[i] = Bv_[(br + i*16)*8 + pc]; \
      _Pragma("unroll") for (int mi = 0; mi < 4; ++mi)                           \
        _Pragma("unroll") for (int ni = 0; ni < 4; ++ni)                         \
          acc[mi][ni] = __builtin_amdgcn_mfma_f32_16x16x32_bf16(af[mi], bfv[ni], acc[mi][ni], 0, 0, 0); \
    }                                                                            \
    __syncthreads();                                                             \
  }

// Common per-thread geometry (4 waves, 128x128 tile, BK=64, 128B LDS rows).
#define GEMM_PROLOG64(A_, B_)                                                    \
  const int tid  = threadIdx.x;                                                  \
  const int lane = tid & 63;                                                     \
  const int widx = tid >> 6;                                                     \
  const int wr   = widx >> 1, wc = widx & 1;                                     \
  const int kc = ((lane & 7) ^ ((lane >> 3) & 7)) * 8;                           \
  const __bf16* Ag = (A_) + (size_t)(row0 + widx * 8 + (lane >> 3)) * DIM + kc;  \
  const __bf16* Bg = (B_) + (size_t)(col0 + widx * 8 + (lane >> 3)) * DIM + kc;  \
  char* AsL = (char*)As + widx * 1024;                                           \
  char* BsL = (char*)Bs + widx * 1024;                                           \
  f32x4 acc[4][4] = {};                                                          \
  const int ar = wr * 64 + (lane & 15);                                          \
  const int br = wc * 64 + (lane & 15);                                          \
  const int kg = lane >> 4;

// MODE 3: out f32  = acc + bias + xres   (final residual GEMM)
// MODE 5: out bf16 = acc * ms            (weight combine; batched via blockIdx.z)
// SWZ=1: XCD row-band remap for grid (8,128).
template <int MODE, int SWZ>
__global__ __launch_bounds__(256, 2)
void gemm_bt(const __bf16* __restrict__ A, const __bf16* __restrict__ Bt,
             const float* __restrict__ bias, void* __restrict__ outp,
             const float* __restrict__ mscp, const float* __restrict__ xres,
             const __bf16* __restrict__ A2, const __bf16* __restrict__ Bt2,
             void* __restrict__ out2)
{
  __shared__ __bf16 As[128 * 64];   // 16 KB
  __shared__ __bf16 Bs[128 * 64];
  if (MODE == 5 && blockIdx.z == 1) { A = A2; Bt = Bt2; outp = out2; }

  int row_t, col_t;
  if (SWZ == 1) {
    const int b = blockIdx.y * 8 + blockIdx.x;   // grid (8,128)
    const int xcd = b & 7, slot = b >> 3;
    col_t = slot & 7;
    row_t = (xcd << 4) | (slot >> 3);
  } else {
    row_t = blockIdx.y; col_t = blockIdx.x;
  }
  const int row0 = row_t * 128, col0 = col_t * 128;

  GEMM_PROLOG64(A, Bt)
  KLOOP64(As, Bs, Ag, Bg, AsL, BsL)

  // C/D frag mapping (HW-verified): col = lane&15, row = (lane>>4)*4 + r
  const int ccol = col0 + wc * 64 + (lane & 15);
  const int crow = row0 + wr * 64 + kg * 4;
  float bvv[4];
  if (MODE != 5) {
#pragma unroll
    for (int ni = 0; ni < 4; ++ni) bvv[ni] = bias[ccol + ni * 16];
  }
  float ms = 0.f;
  if (MODE == 5) ms = mscp[0];
#pragma unroll
  for (int mi = 0; mi < 4; ++mi)
#pragma unroll
    for (int ni = 0; ni < 4; ++ni)
#pragma unroll
      for (int r = 0; r < 4; ++r) {
        const int row = crow + mi * 16 + r;
        const int col = ccol + ni * 16;
        const size_t idx = (size_t)row * DIM + col;
        if (MODE == 3) {
          ((float*)outp)[idx] = acc[mi][ni][r] + bvv[ni] + xres[idx];
        } else {  // MODE 5
          ((__bf16*)outp)[idx] = (__bf16)(acc[mi][ni][r] * ms);
        }
      }
}

// Fused x-GEMM: C[16384, 3072] = xb @ Ball^T, Ball rows = [WvT | WkmP | WqmP].
// Uniform epilogue: out = bf16(acc + bias); base add + wrap deferred to phasor.
// Grid (24,128). XCD band swizzle, ROW-fastest within XCD: 16 co-resident
// row-panels (4 MB A, L2-resident across col sweeps) + streamed 256 KB B tiles.
__global__ __launch_bounds__(256, 2)
void gemm3(const __bf16* __restrict__ A, const __bf16* __restrict__ Ball,
           const float* __restrict__ biasAll,
           __bf16* __restrict__ valb, __bf16* __restrict__ kphb,
           __bf16* __restrict__ qphb)
{
  __shared__ __bf16 As[128 * 64];
  __shared__ __bf16 Bs[128 * 64];
  const int b = blockIdx.y * 24 + blockIdx.x;   // linear id, grid (24,128)
  const int xcd = b & 7, p = b >> 3;            // p in [0,384), bijective
  const int col_t = p / 16;                     // col changes slowest
  const int row_t = (xcd << 4) + (p & 15);      // row-fastest within XCD band
  const int row0 = row_t * 128, col0 = col_t * 128;

  GEMM_PROLOG64(A, Ball)
  KLOOP64(As, Bs, Ag, Bg, AsL, BsL)

  const int band = col_t >> 3;                  // 0:V 1:kph 2:qph
  const int ccol = col0 + wc * 64 + (lane & 15);
  const int lcol0 = ccol & 1023;                // col within the 1024-band
  const int crow = row0 + wr * 64 + kg * 4;
  float bvv[4];
#pragma unroll
  for (int ni = 0; ni < 4; ++ni) bvv[ni] = biasAll[ccol + ni * 16];
  __bf16* outb = (band == 0) ? valb : (band == 1) ? kphb : qphb;
#pragma unroll
  for (int mi = 0; mi < 4; ++mi)
#pragma unroll
    for (int ni = 0; ni < 4; ++ni)
#pragma unroll
      for (int r = 0; r < 4; ++r) {
        const int row = crow + mi * 16 + r;
        const size_t idx = (size_t)row * DIM + lcol0 + ni * 16;
        outb[idx] = (__bf16)(acc[mi][ni][r] + bvv[ni]);
      }
}

// Per chunk (64 rows) x full D: phase = baseb[row&4095] + mod (both bf16);
// in-register cumsum of value*e^{i*kph}, retrieve with qph, /sqrt(D),
// per-row LayerNorm, emit bf16 normed. 8-row batches: 8 independent shfl
// reduce chains interleave (ILP), barriers 128 -> 16.
__global__ __launch_bounds__(256)
void phasor_ln(const __bf16* __restrict__ val, const __bf16* __restrict__ kph,
               const __bf16* __restrict__ qph, const __bf16* __restrict__ baseb,
               const float* __restrict__ g, const float* __restrict__ lb,
               __bf16* __restrict__ nb)
{
  const int t = threadIdx.x;
  const int w = t >> 6, lane = t & 63;
  const size_t r0 = (size_t)blockIdx.x * CHUNK;
  const int c = t * 4;
  const f32x4 gv  = ((const f32x4*)g)[t];
  const f32x4 lbv = ((const f32x4*)lb)[t];
  __shared__ float redS[8][4], redQ[8][4];
  float mr[4] = {0.f, 0.f, 0.f, 0.f};
  float mi[4] = {0.f, 0.f, 0.f, 0.f};
  for (int rb = 0; rb < 8; ++rb) {
    float ret[8][4], ss[8], qq[8];
#pragma unroll
    for (int r = 0; r < 8; ++r) {
      const int row = rb * 8 + r;
      const size_t base = (r0 + row) * DIM + c;
      const f32x4 v  = ld4f(val + base);
      const f32x4 kp = ld4f(kph + base);
      const f32x4 qp = ld4f(qph + base);
      const f32x4 bp = ld4f(baseb + (size_t)((r0 + row) & (SEQ - 1)) * DIM + c);
      float s = 0.f, q = 0.f;
#pragma unroll
      for (int j = 0; j < 4; ++j) {
        float sk, ck, sq, cq;
        __sincosf(bp[j] + kp[j], &sk, &ck);
        mr[j] += v[j] * ck;
        mi[j] += v[j] * sk;
        __sincosf(bp[j] + qp[j], &sq, &cq);
        ret[r][j] = (mr[j] * cq + mi[j] * sq) * 0.03125f;   // 1/sqrt(1024)
        s += ret[r][j];
        q += ret[r][j] * ret[r][j];
      }
      ss[r] = s; qq[r] = q;
    }
#pragma unroll
    for (int off = 32; off > 0; off >>= 1)
#pragma unroll
      for (int r = 0; r < 8; ++r) {
        ss[r] += __shfl_down(ss[r], off);
        qq[r] += __shfl_down(qq[r], off);
      }
    if (lane == 0)
#pragma unroll
      for (int r = 0; r < 8; ++r) { redS[r][w] = ss[r]; redQ[r][w] = qq[r]; }
    __syncthreads();
#pragma unroll
    for (int r = 0; r < 8; ++r) {
      const float mu   = (redS[r][0] + redS[r][1] + redS[r][2] + redS[r][3]) * (1.0f / DIM);
      const float varr = (redQ[r][0] + redQ[r][1] + redQ[r][2] + redQ[r][3]) * (1.0f / DIM) - mu * mu;
      const float rinv = rsqrtf(varr + 1e-5f);
      bf16x4 o;
#pragma unroll
      for (int j = 0; j < 4; ++j) o[j] = (__bf16)((ret[r][j] - mu) * rinv * gv[j] + lbv[j]);
      *(bf16x4*)(nb + (r0 + rb * 8 + r) * DIM + c) = o;
    }
    __syncthreads();   // protect redS/redQ before next batch
  }
}

// fp32 -> bf16, 4/thread
__global__ void f2b_kernel(const float* __restrict__ in, __bf16* __restrict__ out, int n4) {
  int i = blockIdx.x * 256 + threadIdx.x;
  if (i >= n4) return;
  f32x4 vv = ((const f32x4*)in)[i];
  bf16x4 o;
#pragma unroll
  for (int j = 0; j < 4; ++j) o[j] = (__bf16)vv[j];
  ((bf16x4*)out)[i] = o;
}

// fp32 -> wrapped-to-[-pi,pi] bf16 (for base_phases)
__global__ void wrapb_kernel(const float* __restrict__ in, __bf16* __restrict__ out, int n4) {
  int i = blockIdx.x * 256 + threadIdx.x;
  if (i >= n4) return;
  f32x4 vv = ((const f32x4*)in)[i];
  bf16x4 o;
#pragma unroll
  for (int j = 0; j < 4; ++j) {
    float v = vv[j];
    v -= 6.2831853f * rintf(v * 0.15915494f);
    o[j] = (__bf16)v;
  }
  ((bf16x4*)out)[i] = o;
}

// fp32 -> bf16, two tensors batched on blockIdx.y
__global__ void f2b2_kernel(const float* __restrict__ i0, __bf16* __restrict__ o0,
                            const float* __restrict__ i1, __bf16* __restrict__ o1, int n4) {
  int i = blockIdx.x * 256 + threadIdx.x;
  if (i >= n4) return;
  const float* in = blockIdx.y ? i1 : i0;
  __bf16* out = blockIdx.y ? o1 : o0;
  f32x4 vv = ((const f32x4*)in)[i];
  bf16x4 o;
#pragma unroll
  for (int j = 0; j < 4; ++j) o[j] = (__bf16)vv[j];
  ((bf16x4*)out)[i] = o;
}

// Wt[n][k] = (bf16) W[k][n], 4 matrices batched on blockIdx.z
__global__ void transpose_f2b4(const float* __restrict__ s0, __bf16* __restrict__ d0,
                               const float* __restrict__ s1, __bf16* __restrict__ d1,
                               const float* __restrict__ s2, __bf16* __restrict__ d2,
                               const float* __restrict__ s3, __bf16* __restrict__ d3) {
  __shared__ float tle[32][33];
  const float* W; __bf16* Wt;
  switch (blockIdx.z) {
    case 0: W = s0; Wt = d0; break;
    case 1: W = s1; Wt = d1; break;
    case 2: W = s2; Wt = d2; break;
    default: W = s3; Wt = d3; break;
  }
  const int tx = threadIdx.x, ty = threadIdx.y;
  const int bx = blockIdx.x * 32, by = blockIdx.y * 32;
  for (int i = ty; i < 32; i += 8) tle[i][tx] = W[(size_t)(by + i) * DIM + bx + tx];
  __syncthreads();
  for (int i = ty; i < 32; i += 8) Wt[(size_t)(bx + i) * DIM + by + tx] = (__bf16)tle[tx][i];
}

// biasAll init: [0,1024)=bv; [1024,2048)=bkm*ms; [2048,3072)=bqm*ms
__global__ void biasinit(const float* __restrict__ bv, const float* __restrict__ bkm,
                         const float* __restrict__ bqm, const float* __restrict__ ms,
                         float* __restrict__ biasAll) {
  const int n = blockIdx.x * 256 + threadIdx.x;
  const float m = ms[0];
  biasAll[n] = bv[n];
  biasAll[1024 + n] = bkm[n] * m;
  biasAll[2048 + n] = bqm[n] * m;
}

// k-parallel bias combine: biasAll[1024+which*1024+n] += ms * sum_k bs[k]*W[k][n]
// grid (1,2,8) x 256: blockIdx.y = which, blockIdx.z = k-segment of 128
__global__ void biasacc(const float* __restrict__ bk, const float* __restrict__ Wkm,
                        const float* __restrict__ bq, const float* __restrict__ Wqm,
                        const float* __restrict__ ms, float* __restrict__ biasAll) {
  const int t = threadIdx.x;
  const int which = blockIdx.y;
  const int k0 = blockIdx.z * 128;
  const float* bs = which ? bq : bk;
  const float* W  = which ? Wqm : Wkm;
  const int n0 = t * 4;
  float s0 = 0.f, s1 = 0.f, s2 = 0.f, s3 = 0.f;
  for (int k = k0; k < k0 + 128; ++k) {
    const float b = bs[k];
    const f32x4 wv = *(const f32x4*)(W + (size_t)k * DIM + n0);
    s0 += b * wv[0]; s1 += b * wv[1]; s2 += b * wv[2]; s3 += b * wv[3];
  }
  const float m = ms[0];
  float* dst = biasAll + 1024 + which * 1024 + n0;
  atomicAdd(dst + 0, s0 * m);
  atomicAdd(dst + 1, s1 * m);
  atomicAdd(dst + 2, s2 * m);
  atomicAdd(dst + 3, s3 * m);
}

// diagnostic fallback: out = x (absmax ~6.5 signals "workspace too small")
__global__ void copyx_kernel(const float* __restrict__ x, float* __restrict__ out, int n4) {
  int i = blockIdx.x * 256 + threadIdx.x;
  if (i >= n4) return;
  ((f32x4*)out)[i] = ((const f32x4*)x)[i];
}

extern "C" void kernel_launch(void* const* d_in, const int* in_sizes, int n_in,
                              void* d_out, int out_size, void* d_ws, size_t ws_size,
                              hipStream_t stream)
{
  (void)in_sizes; (void)n_in; (void)out_size;
  const float* x     = (const float*)d_in[0];
  const float* basep = (const float*)d_in[1];
  const float* Wk    = (const float*)d_in[2];
  const float* bk    = (const float*)d_in[3];
  const float* Wv    = (const float*)d_in[4];
  const float* bv    = (const float*)d_in[5];
  const float* Wq    = (const float*)d_in[6];
  const float* bq    = (const float*)d_in[7];
  const float* Wkm   = (const float*)d_in[8];
  const float* bkm   = (const float*)d_in[9];
  const float* Wqm   = (const float*)d_in[10];
  const float* bqm   = (const float*)d_in[11];
  const float* msc   = (const float*)d_in[12];
  const float* lng   = (const float*)d_in[13];
  const float* lnb   = (const float*)d_in[14];
  const float* Wo    = (const float*)d_in[15];
  const float* bo    = (const float*)d_in[16];

  char* ws = (char*)d_ws;
  const size_t MB = 1ull << 20;
  if (ws_size < 153 * MB) {
    copyx_kernel<<<MROWS * DIM / 4 / 256, 256, 0, stream>>>(x, (float*)d_out, MROWS * DIM / 4);
    return;
  }

  // layout (152 MB + 12 KB):
  __bf16* xb     = (__bf16*)ws;              // [0,32)   x bf16; nbuf aliases it after use
  __bf16* valb   = (__bf16*)(ws +  32 * MB); // [32,64)
  __bf16* kphb   = (__bf16*)(ws +  64 * MB); // [64,96)  mod-only phase (tiny values)
  __bf16* qphb   = (__bf16*)(ws +  96 * MB); // [96,128)
  __bf16* Ball   = (__bf16*)(ws + 128 * MB); // [128,134) rows: WvT | WkmP | WqmP
  __bf16* WoT    = (__bf16*)(ws + 134 * MB); // [134,136)
  __bf16* TWkm   = (__bf16*)(ws + 136 * MB); // [136,138)
  __bf16* BWk    = (__bf16*)(ws + 138 * MB); // [138,140)
  __bf16* TWqm   = (__bf16*)(ws + 140 * MB); // [140,142)
  __bf16* BWq    = (__bf16*)(ws + 142 * MB); // [142,144)
  __bf16* baseb  = (__bf16*)(ws + 144 * MB); // [144,152) wrapped base_phases bf16
  float*  biasAll= (float*)(ws + 152 * MB);  // 12 KB
  __bf16* nbuf   = xb;

  // --- preps (batched) ---
  f2b_kernel<<<MROWS * DIM / 4 / 256, 256, 0, stream>>>(x, xb, MROWS * DIM / 4);
  wrapb_kernel<<<SEQ * DIM / 4 / 256, 256, 0, stream>>>(basep, baseb, SEQ * DIM / 4);
  dim3 tg(32, 32, 4), tb(32, 8);
  transpose_f2b4<<<tg, tb, 0, stream>>>(Wv, Ball, Wo, WoT, Wkm, TWkm, Wqm, TWqm);
  f2b2_kernel<<<dim3(DIM * DIM / 4 / 256, 2), 256, 0, stream>>>(Wk, BWk, Wq, BWq, DIM * DIM / 4);
  // weight combines -> Ball rows [1024,2048) and [2048,3072)
  gemm_bt<5, 0><<<dim3(8, 8, 2), 256, 0, stream>>>(
      TWkm, BWk, nullptr, Ball + (size_t)1024 * DIM, msc, nullptr,
      TWqm, BWq, Ball + (size_t)2048 * DIM);
  biasinit<<<4, 256, 0, stream>>>(bv, bkm, bqm, msc, biasAll);
  biasacc<<<dim3(1, 2, 8), 256, 0, stream>>>(bk, Wkm, bq, Wqm, msc, biasAll);

  // --- main pipeline ---
  gemm3<<<dim3(24, 128), 256, 0, stream>>>(xb, Ball, biasAll, valb, kphb, qphb);
  phasor_ln<<<NCHUNKBLKS, 256, 0, stream>>>(valb, kphb, qphb, baseb, lng, lnb, nbuf);
  gemm_bt<3, 1><<<dim3(8, 128), 256, 0, stream>>>(
      nbuf, WoT, bo, d_out, nullptr, x, nullptr, nullptr, nullptr);
}